// Round 6
// baseline (226.740 us; speedup 1.0000x reference)
//
#include <hip/hip_runtime.h>

// ChamferLoss: x,y [4, 8192, 3] fp32 -> scalar fp32.
// out = (sum_bn min_m d2 + sum_bm min_n d2) / 32768
//
// Round 6: R5's LDS-broadcast sweep was right (TCP bypassed) but ran as ONE
// 16-wave 64KB-LDS block per CU: 4 waves/SIMD, lockstep barriers, ~20us
// no-issue stall. Same math, restructured for overlap: 512 blocks x 512 thr
// (8 waves), 1024 queries/block (Q=16 per LANE - query capacity is per-lane),
// 512 records staged (16KB), epilogue red[8][512] in two lane-half rounds
// (16KB union) -> 4 independent blocks/CU = 32 waves/CU = 8 waves/SIMD.
// Register double-buffer on the record stream decouples lgkm waits.
// Math cell (verified R4/R5): v_pk_fma_f32 + op_sel cross-swap,
// 2-query x 2-point in 6 pk_fma + 2 v_min3 = 2.0 inst/pair.

#define N_      8192
#define NQ      65536         // total queries (2 sides)
#define FLT_BIG 3.0e38f

typedef float v2f __attribute__((ext_vector_type(2)));

__global__ void zero_out_kernel(float* out) { *out = 0.0f; }

// ---------------- init: pmin = +inf ----------------
__global__ __launch_bounds__(256) void init_kernel(unsigned int* __restrict__ pmin)
{
    int i = blockIdx.x * 256 + threadIdx.x;    // grid 64 -> 16384 uint4
    ((uint4*)pmin)[i] = make_uint4(0x7F800000u, 0x7F800000u, 0x7F800000u, 0x7F800000u);
}

// ---------------- main ----------------
// 512 blocks x 512 thr. blk = {dir[1], batch[2], qg[3], seg[3]}.
// Block: queries qbase..qbase+1023 (16/lane, all waves hold the same 1024),
// opposite-point segment of 512 records (1024 points) staged in LDS.
// Wave w sweeps records [w*64, w*64+64).

__global__ __launch_bounds__(512, 8) void chamfer_kernel(
    const float* __restrict__ xraw, const float* __restrict__ yraw,
    unsigned int* __restrict__ pmin)
{
    // 16 KB union: phase A = 1024 float4 packed records;
    // phase B = red[8][512] floats (two rounds), after barriers.
    __shared__ float4 lds4[1024];

    const int tid  = threadIdx.x;
    const int lane = tid & 63;
    const int wave = __builtin_amdgcn_readfirstlane(tid >> 6);
    const int blk  = blockIdx.x;               // 0..511
    const int dir   = blk >> 8;                // 0: x-queries vs y, 1: y vs x
    const int batch = (blk >> 6) & 3;
    const int qg    = (blk >> 3) & 7;          // query group (1024 q)
    const int seg   = blk & 7;                 // record segment (512 recs)

    const float* qraw = dir ? yraw : xraw;
    const float* oraw = dir ? xraw : yraw;

    // ---- stage: pack 512 records {x0,x1,y0,y1}{z0,z1,w0,w1}, 1/thread ----
    {
        int r = tid;                           // 0..511
        const float2* p2 = (const float2*)(oraw + ((size_t)batch * N_ + seg * 1024 + 2 * r) * 3);
        float2 a = p2[0], b = p2[1], c = p2[2];   // x0,y0 | z0,x1 | y1,z1
        float w0 = fmaf(a.x, a.x, fmaf(a.y, a.y, b.x * b.x));
        float w1 = fmaf(b.y, b.y, fmaf(c.x, c.x, c.y * c.y));
        lds4[2*r]   = make_float4(a.x, b.y, a.y, c.x);
        lds4[2*r+1] = make_float4(b.x, c.y, w0, w1);
    }

    // ---- load this lane's 16 queries (48 contiguous floats) ----
    const int qbase = batch * N_ + qg * 1024;
    v2f qx[8], qy[8], qz[8];
    float acc[16];
    {
        float f[48];
        const float4* qv = (const float4*)(qraw + (size_t)qbase * 3) + lane * 12;
        #pragma unroll
        for (int k = 0; k < 12; ++k) {
            float4 t = qv[k];
            f[4*k] = t.x; f[4*k+1] = t.y; f[4*k+2] = t.z; f[4*k+3] = t.w;
        }
        #pragma unroll
        for (int j = 0; j < 8; ++j) {
            qx[j] = (v2f){-2.0f * f[6*j+0], -2.0f * f[6*j+3]};
            qy[j] = (v2f){-2.0f * f[6*j+1], -2.0f * f[6*j+4]};
            qz[j] = (v2f){-2.0f * f[6*j+2], -2.0f * f[6*j+5]};
            acc[2*j] = FLT_BIG; acc[2*j+1] = FLT_BIG;
        }
    }
    __syncthreads();

    // ---- sweep: 64 records from LDS, broadcast reads, reg double-buffer ----
    const float4* rp = lds4 + wave * 128;      // this wave's 64 records
    float4 u = rp[0], v = rp[1];
    for (int k = 0; k < 64; ++k) {
        float4 un, vn;
        if (k < 63) { un = rp[2*k+2]; vn = rp[2*k+3]; }
        v2f px = (v2f){u.x, u.y};
        v2f py = (v2f){u.z, u.w};
        v2f pz = (v2f){v.x, v.y};
        v2f w2 = (v2f){v.z, v.w};
        #pragma unroll
        for (int j = 0; j < 8; ++j) {
            v2f td, ts;
            // td = {q0p0+w0, q1p1+w1}; ts = {q0p1+w1, q1p0+w0} via op_sel swap
            asm("v_pk_fma_f32 %0, %1, %2, %3"
                : "=v"(td) : "v"(qz[j]), "v"(pz), "v"(w2));
            asm("v_pk_fma_f32 %0, %1, %2, %3 op_sel:[0,1,1] op_sel_hi:[1,0,0]"
                : "=v"(ts) : "v"(qz[j]), "v"(pz), "v"(w2));
            asm("v_pk_fma_f32 %0, %1, %2, %0"
                : "+v"(td) : "v"(qy[j]), "v"(py));
            asm("v_pk_fma_f32 %0, %1, %2, %0 op_sel:[0,1,0] op_sel_hi:[1,0,1]"
                : "+v"(ts) : "v"(qy[j]), "v"(py));
            asm("v_pk_fma_f32 %0, %1, %2, %0"
                : "+v"(td) : "v"(qx[j]), "v"(px));
            asm("v_pk_fma_f32 %0, %1, %2, %0 op_sel:[0,1,0] op_sel_hi:[1,0,1]"
                : "+v"(ts) : "v"(qx[j]), "v"(px));
            asm("v_min3_f32 %0, %0, %1, %2" : "+v"(acc[2*j])   : "v"(td.x), "v"(ts.x));
            asm("v_min3_f32 %0, %0, %1, %2" : "+v"(acc[2*j+1]) : "v"(td.y), "v"(ts.y));
        }
        u = un; v = vn;
    }

    // ---- epilogue: two rounds (lane-halves), red[8][512] overlays lds4 ----
    float* red = (float*)lds4;
    #pragma unroll
    for (int r = 0; r < 2; ++r) {
        __syncthreads();                       // staging/prev-round reads done
        if ((lane >> 5) == r) {
            float4* rw = (float4*)&red[wave * 512 + (lane & 31) * 16];
            rw[0] = make_float4(acc[0],  acc[1],  acc[2],  acc[3]);
            rw[1] = make_float4(acc[4],  acc[5],  acc[6],  acc[7]);
            rw[2] = make_float4(acc[8],  acc[9],  acc[10], acc[11]);
            rw[3] = make_float4(acc[12], acc[13], acc[14], acc[15]);
        }
        __syncthreads();
        // thread t owns block-query r*512 + t
        float m = red[tid];
        #pragma unroll
        for (int w = 1; w < 8; ++w) m = fminf(m, red[w * 512 + tid]);
        int gq = qbase + r * 512 + tid;
        float ax = qraw[gq*3+0], ay = qraw[gq*3+1], az = qraw[gq*3+2];
        float qn = fmaf(ax, ax, fmaf(ay, ay, az * az));
        float d2 = fmaxf(0.0f, qn + m);        // relu commutes with min
        atomicMin(&pmin[dir * 32768 + gq], __float_as_uint(d2));
    }
}

// ---------------- sum: single block, deterministic ----------------
__global__ __launch_bounds__(1024) void sum_kernel(
    const unsigned int* __restrict__ pmin, float* __restrict__ out)
{
    __shared__ float sred[16];
    const int tid = threadIdx.x;
    const float4* pv = (const float4*)pmin;    // bits are valid non-neg floats
    float s = 0.0f;
    #pragma unroll
    for (int k = 0; k < 16; ++k) {             // 16384 float4 / 1024 threads
        float4 v = pv[k * 1024 + tid];
        s += v.x + v.y + v.z + v.w;
    }
    #pragma unroll
    for (int off = 32; off > 0; off >>= 1) s += __shfl_xor(s, off);
    if ((tid & 63) == 0) sred[tid >> 6] = s;
    __syncthreads();
    if (tid < 16) {
        float v = sred[tid];
        #pragma unroll
        for (int off = 8; off > 0; off >>= 1) v += __shfl_xor(v, off);
        if (tid == 0) *out = v * (1.0f / 32768.0f);
    }
}

// ---------------- fallback (ws too small): round-1 kernel ----------------
__global__ __launch_bounds__(1024) void chamfer_raw_kernel(
    const float* __restrict__ xraw, const float* __restrict__ yraw,
    float* __restrict__ out)
{
    __shared__ float4 red4[16][64];
    const int tid  = threadIdx.x;
    const int wave = tid >> 6;
    const int lane = tid & 63;
    const int blk  = blockIdx.x;
    const bool xdir = (blk < 128);
    const int b    = (blk & 127) >> 5;
    const int qofs = (blk & 31) << 8;
    const float* qraw = xdir ? xraw : yraw;
    const float* oraw = xdir ? yraw : xraw;
    float qx0[4], qx1[4], qx2[4], acc[4];
    #pragma unroll
    for (int q = 0; q < 4; ++q) {
        int gq = b * N_ + qofs + lane*4 + q;
        qx0[q] = qraw[gq*3+0]; qx1[q] = qraw[gq*3+1]; qx2[q] = qraw[gq*3+2];
        acc[q] = FLT_BIG;
    }
    const float* opp = oraw + (size_t)(b * N_ + wave * 512) * 3;
    #pragma unroll 4
    for (int k = 0; k < 512; ++k) {
        float p0 = opp[k*3+0], p1 = opp[k*3+1], p2 = opp[k*3+2];
        float w  = fmaf(p0, p0, fmaf(p1, p1, p2*p2));
        #pragma unroll
        for (int q = 0; q < 4; ++q) {
            float dot = qx0[q]*p0 + qx1[q]*p1 + qx2[q]*p2;
            acc[q] = fminf(acc[q], fmaf(-2.0f, dot, w));
        }
    }
    red4[wave][lane] = make_float4(acc[0], acc[1], acc[2], acc[3]);
    __syncthreads();
    if (tid < 256) {
        const float* red = (const float*)red4;
        float m = red[tid];
        #pragma unroll
        for (int w = 1; w < 16; ++w) m = fminf(m, red[w*256 + tid]);
        int gq = b * N_ + qofs + tid;
        float ax = qraw[gq*3+0], ay = qraw[gq*3+1], az = qraw[gq*3+2];
        float d2 = fmaxf(0.0f, fmaf(ax,ax,fmaf(ay,ay,az*az)) + m);
        #pragma unroll
        for (int off = 32; off > 0; off >>= 1) d2 += __shfl_xor(d2, off);
        if ((tid & 63) == 0) atomicAdd(out, d2 * (1.0f / 32768.0f));
    }
}

extern "C" void kernel_launch(void* const* d_in, const int* in_sizes, int n_in,
                              void* d_out, int out_size, void* d_ws, size_t ws_size,
                              hipStream_t stream)
{
    const float* x = (const float*)d_in[0];
    const float* y = (const float*)d_in[1];
    float* out = (float*)d_out;

    const size_t need = (size_t)NQ * 4;        // 256 KB pmin
    if (ws_size >= need) {
        unsigned int* pmin = (unsigned int*)d_ws;
        init_kernel<<<64, 256, 0, stream>>>(pmin);
        chamfer_kernel<<<512, 512, 0, stream>>>(x, y, pmin);
        sum_kernel<<<1, 1024, 0, stream>>>(pmin, out);
    } else {
        zero_out_kernel<<<1, 1, 0, stream>>>(out);
        chamfer_raw_kernel<<<256, 1024, 0, stream>>>(x, y, out);
    }
}

// Round 7
// 100.848 us; speedup vs baseline: 2.2483x; 2.2483x over previous
//
#include <hip/hip_runtime.h>

// ChamferLoss: x,y [4, 8192, 3] fp32 -> scalar fp32.
// out = (sum_bn min_m d2 + sum_bm min_n d2) / 32768
//
// Round 7: R6's idea (multiple independent blocks/CU to overlap staging/
// epilogue stalls) was killed by its own __launch_bounds__(512,8): VGPR cap
// 64 < ~84 needed at Q=16 -> scratch spill (FETCH 15.7MB, WRITE 26.6MB,
// VALUBusy 16%). Fix: __launch_bounds__(512,4) (cap 128, no spill, 2
// co-resident 8-wave blocks/CU) and 1024 blocks x 512 thr (seg=16, 256
// records staged = 8KB; LDS union 16KB) so 2 resident + 2 queued blocks
// per CU overlap barriers and hide stragglers.
// Math cell (verified R4/R5/R6): v_pk_fma_f32 + op_sel cross-swap,
// 2-query x 2-point in 6 pk_fma + 2 v_min3. LDS broadcast sweep (R5).

#define N_      8192
#define NQ      65536         // total queries (2 sides)
#define FLT_BIG 3.0e38f

typedef float v2f __attribute__((ext_vector_type(2)));

__global__ void zero_out_kernel(float* out) { *out = 0.0f; }

// ---------------- init: pmin = +inf ----------------
__global__ __launch_bounds__(256) void init_kernel(unsigned int* __restrict__ pmin)
{
    int i = blockIdx.x * 256 + threadIdx.x;    // grid 64 -> 16384 uint4
    ((uint4*)pmin)[i] = make_uint4(0x7F800000u, 0x7F800000u, 0x7F800000u, 0x7F800000u);
}

// ---------------- main ----------------
// 1024 blocks x 512 thr. blk = {dir[1], batch[2], qg[3], seg[4]}.
// Block: queries qbase..qbase+1023 (Q=16 per lane, all waves hold the same
// 1024), opposite segment of 256 records (512 points) staged in LDS.
// Wave w sweeps records [w*32, w*32+32).

__global__ __launch_bounds__(512, 4) void chamfer_kernel(
    const float* __restrict__ xraw, const float* __restrict__ yraw,
    unsigned int* __restrict__ pmin)
{
    // 16 KB union: phase A = 512 float4 (256 packed records, 8 KB used);
    // phase B = red[8][512] floats (16 KB), after barriers.
    __shared__ float4 lds4[1024];

    const int tid  = threadIdx.x;
    const int lane = tid & 63;
    const int wave = __builtin_amdgcn_readfirstlane(tid >> 6);
    const int blk  = blockIdx.x;               // 0..1023
    const int dir   = blk >> 9;                // 0: x-queries vs y, 1: y vs x
    const int batch = (blk >> 7) & 3;
    const int qg    = (blk >> 4) & 7;          // query group (1024 q)
    const int seg   = blk & 15;                // record segment (256 recs)

    const float* qraw = dir ? yraw : xraw;
    const float* oraw = dir ? xraw : yraw;

    // ---- stage: pack 256 records {x0,x1,y0,y1}{z0,z1,w0,w1} ----
    if (tid < 256) {
        int r = tid;
        const float2* p2 = (const float2*)(oraw + ((size_t)batch * N_ + seg * 512 + 2 * r) * 3);
        float2 a = p2[0], b = p2[1], c = p2[2];   // x0,y0 | z0,x1 | y1,z1
        float w0 = fmaf(a.x, a.x, fmaf(a.y, a.y, b.x * b.x));
        float w1 = fmaf(b.y, b.y, fmaf(c.x, c.x, c.y * c.y));
        lds4[2*r]   = make_float4(a.x, b.y, a.y, c.x);
        lds4[2*r+1] = make_float4(b.x, c.y, w0, w1);
    }

    // ---- load this lane's 16 queries (48 contiguous floats) ----
    const int qbase = batch * N_ + qg * 1024;
    v2f qx[8], qy[8], qz[8];
    float acc[16];
    {
        float f[48];
        const float4* qv = (const float4*)(qraw + (size_t)qbase * 3) + lane * 12;
        #pragma unroll
        for (int k = 0; k < 12; ++k) {
            float4 t = qv[k];
            f[4*k] = t.x; f[4*k+1] = t.y; f[4*k+2] = t.z; f[4*k+3] = t.w;
        }
        #pragma unroll
        for (int j = 0; j < 8; ++j) {
            qx[j] = (v2f){-2.0f * f[6*j+0], -2.0f * f[6*j+3]};
            qy[j] = (v2f){-2.0f * f[6*j+1], -2.0f * f[6*j+4]};
            qz[j] = (v2f){-2.0f * f[6*j+2], -2.0f * f[6*j+5]};
            acc[2*j] = FLT_BIG; acc[2*j+1] = FLT_BIG;
        }
    }
    __syncthreads();

    // ---- sweep: 32 records from LDS, broadcast reads ----
    const float4* rp = lds4 + wave * 64;       // this wave's 32 records
    #pragma unroll 8
    for (int k = 0; k < 32; ++k) {
        float4 u = rp[2*k];                    // {x0,x1,y0,y1}
        float4 v = rp[2*k+1];                  // {z0,z1,w0,w1}
        v2f px = (v2f){u.x, u.y};
        v2f py = (v2f){u.z, u.w};
        v2f pz = (v2f){v.x, v.y};
        v2f w2 = (v2f){v.z, v.w};
        #pragma unroll
        for (int j = 0; j < 8; ++j) {
            v2f td, ts;
            // td = {q0p0+w0, q1p1+w1}; ts = {q0p1+w1, q1p0+w0} via op_sel swap
            asm("v_pk_fma_f32 %0, %1, %2, %3"
                : "=v"(td) : "v"(qz[j]), "v"(pz), "v"(w2));
            asm("v_pk_fma_f32 %0, %1, %2, %3 op_sel:[0,1,1] op_sel_hi:[1,0,0]"
                : "=v"(ts) : "v"(qz[j]), "v"(pz), "v"(w2));
            asm("v_pk_fma_f32 %0, %1, %2, %0"
                : "+v"(td) : "v"(qy[j]), "v"(py));
            asm("v_pk_fma_f32 %0, %1, %2, %0 op_sel:[0,1,0] op_sel_hi:[1,0,1]"
                : "+v"(ts) : "v"(qy[j]), "v"(py));
            asm("v_pk_fma_f32 %0, %1, %2, %0"
                : "+v"(td) : "v"(qx[j]), "v"(px));
            asm("v_pk_fma_f32 %0, %1, %2, %0 op_sel:[0,1,0] op_sel_hi:[1,0,1]"
                : "+v"(ts) : "v"(qx[j]), "v"(px));
            asm("v_min3_f32 %0, %0, %1, %2" : "+v"(acc[2*j])   : "v"(td.x), "v"(ts.x));
            asm("v_min3_f32 %0, %0, %1, %2" : "+v"(acc[2*j+1]) : "v"(td.y), "v"(ts.y));
        }
    }

    // ---- epilogue: two rounds (lane-halves), red[8][512] overlays lds4 ----
    float* red = (float*)lds4;
    #pragma unroll
    for (int r = 0; r < 2; ++r) {
        __syncthreads();                       // staging/prev-round reads done
        if ((lane >> 5) == r) {
            float4* rw = (float4*)&red[wave * 512 + (lane & 31) * 16];
            rw[0] = make_float4(acc[0],  acc[1],  acc[2],  acc[3]);
            rw[1] = make_float4(acc[4],  acc[5],  acc[6],  acc[7]);
            rw[2] = make_float4(acc[8],  acc[9],  acc[10], acc[11]);
            rw[3] = make_float4(acc[12], acc[13], acc[14], acc[15]);
        }
        __syncthreads();
        // thread t owns block-query r*512 + t
        float m = red[tid];
        #pragma unroll
        for (int w = 1; w < 8; ++w) m = fminf(m, red[w * 512 + tid]);
        int gq = qbase + r * 512 + tid;
        float ax = qraw[gq*3+0], ay = qraw[gq*3+1], az = qraw[gq*3+2];
        float qn = fmaf(ax, ax, fmaf(ay, ay, az * az));
        float d2 = fmaxf(0.0f, qn + m);        // relu commutes with min
        atomicMin(&pmin[dir * 32768 + gq], __float_as_uint(d2));
    }
}

// ---------------- sum: single block, deterministic ----------------
__global__ __launch_bounds__(1024) void sum_kernel(
    const unsigned int* __restrict__ pmin, float* __restrict__ out)
{
    __shared__ float sred[16];
    const int tid = threadIdx.x;
    const float4* pv = (const float4*)pmin;    // bits are valid non-neg floats
    float s = 0.0f;
    #pragma unroll
    for (int k = 0; k < 16; ++k) {             // 16384 float4 / 1024 threads
        float4 v = pv[k * 1024 + tid];
        s += v.x + v.y + v.z + v.w;
    }
    #pragma unroll
    for (int off = 32; off > 0; off >>= 1) s += __shfl_xor(s, off);
    if ((tid & 63) == 0) sred[tid >> 6] = s;
    __syncthreads();
    if (tid < 16) {
        float v = sred[tid];
        #pragma unroll
        for (int off = 8; off > 0; off >>= 1) v += __shfl_xor(v, off);
        if (tid == 0) *out = v * (1.0f / 32768.0f);
    }
}

// ---------------- fallback (ws too small): round-1 kernel ----------------
__global__ __launch_bounds__(1024) void chamfer_raw_kernel(
    const float* __restrict__ xraw, const float* __restrict__ yraw,
    float* __restrict__ out)
{
    __shared__ float4 red4[16][64];
    const int tid  = threadIdx.x;
    const int wave = tid >> 6;
    const int lane = tid & 63;
    const int blk  = blockIdx.x;
    const bool xdir = (blk < 128);
    const int b    = (blk & 127) >> 5;
    const int qofs = (blk & 31) << 8;
    const float* qraw = xdir ? xraw : yraw;
    const float* oraw = xdir ? yraw : xraw;
    float qx0[4], qx1[4], qx2[4], acc[4];
    #pragma unroll
    for (int q = 0; q < 4; ++q) {
        int gq = b * N_ + qofs + lane*4 + q;
        qx0[q] = qraw[gq*3+0]; qx1[q] = qraw[gq*3+1]; qx2[q] = qraw[gq*3+2];
        acc[q] = FLT_BIG;
    }
    const float* opp = oraw + (size_t)(b * N_ + wave * 512) * 3;
    #pragma unroll 4
    for (int k = 0; k < 512; ++k) {
        float p0 = opp[k*3+0], p1 = opp[k*3+1], p2 = opp[k*3+2];
        float w  = fmaf(p0, p0, fmaf(p1, p1, p2*p2));
        #pragma unroll
        for (int q = 0; q < 4; ++q) {
            float dot = qx0[q]*p0 + qx1[q]*p1 + qx2[q]*p2;
            acc[q] = fminf(acc[q], fmaf(-2.0f, dot, w));
        }
    }
    red4[wave][lane] = make_float4(acc[0], acc[1], acc[2], acc[3]);
    __syncthreads();
    if (tid < 256) {
        const float* red = (const float*)red4;
        float m = red[tid];
        #pragma unroll
        for (int w = 1; w < 16; ++w) m = fminf(m, red[w*256 + tid]);
        int gq = b * N_ + qofs + tid;
        float ax = qraw[gq*3+0], ay = qraw[gq*3+1], az = qraw[gq*3+2];
        float d2 = fmaxf(0.0f, fmaf(ax,ax,fmaf(ay,ay,az*az)) + m);
        #pragma unroll
        for (int off = 32; off > 0; off >>= 1) d2 += __shfl_xor(d2, off);
        if ((tid & 63) == 0) atomicAdd(out, d2 * (1.0f / 32768.0f));
    }
}

extern "C" void kernel_launch(void* const* d_in, const int* in_sizes, int n_in,
                              void* d_out, int out_size, void* d_ws, size_t ws_size,
                              hipStream_t stream)
{
    const float* x = (const float*)d_in[0];
    const float* y = (const float*)d_in[1];
    float* out = (float*)d_out;

    const size_t need = (size_t)NQ * 4;        // 256 KB pmin
    if (ws_size >= need) {
        unsigned int* pmin = (unsigned int*)d_ws;
        init_kernel<<<64, 256, 0, stream>>>(pmin);
        chamfer_kernel<<<1024, 512, 0, stream>>>(x, y, pmin);
        sum_kernel<<<1, 1024, 0, stream>>>(pmin, out);
    } else {
        zero_out_kernel<<<1, 1, 0, stream>>>(out);
        chamfer_raw_kernel<<<256, 1024, 0, stream>>>(x, y, out);
    }
}

// Round 8
// 100.372 us; speedup vs baseline: 2.2590x; 1.0047x over previous
//
#include <hip/hip_runtime.h>

// ChamferLoss: x,y [4, 8192, 3] fp32 -> scalar fp32.
// out = (sum_bn min_m d2 + sum_bm min_n d2) / 32768
//
// Round 8: v_pk_fma_f32 is HALF-RATE on gfx950 (spec 157.3 TF == scalar-fma
// full issue; pk at full rate would be 314 TF) -> R2-R7's packing premise was
// void; the asm only defeated the scheduler. This round: plain scalar fma +
// min3 (same 7 cyc/directional-eval floor, compiler-schedulable), and
// STRIDED query ownership q = lane + 64*j which fixes three stall sources:
//   - query global loads coalesce (lane-stride 12 B vs 192 B)
//   - epilogue red[q*9+wave]: lane-stride 9 coprime 32 -> conflict-free
//   - qn cached in LDS (stride-1), no epilogue global re-reads
// 512 blocks x 512 thr (8 waves), 2 independent blocks/CU, 3 barriers,
// LDS 40 KB: [0,9216) red floats (records overlay first 4096), [9216,10240) qn.

#define N_      8192
#define NQ      65536         // total queries (2 sides)
#define FLT_BIG 3.0e38f

__global__ void zero_out_kernel(float* out) { *out = 0.0f; }

// ---------------- init: pmin = +inf ----------------
__global__ __launch_bounds__(256) void init_kernel(unsigned int* __restrict__ pmin)
{
    int i = blockIdx.x * 256 + threadIdx.x;    // grid 64 -> 16384 uint4
    ((uint4*)pmin)[i] = make_uint4(0x7F800000u, 0x7F800000u, 0x7F800000u, 0x7F800000u);
}

// ---------------- main ----------------
// 512 blocks x 512 thr. blk = {dir[1], batch[2], qg[3], seg[3]}.
// Block: 1024 queries (16/lane, strided: q = lane + 64j; all 8 waves hold the
// same 1024), 512 opposite records (1024 points) staged in LDS.
// Wave w sweeps records [w*64, w*64+64).

__global__ __launch_bounds__(512, 4) void chamfer_kernel(
    const float* __restrict__ xraw, const float* __restrict__ yraw,
    unsigned int* __restrict__ pmin)
{
    // 40 KB: red = lds[0..9216) (combine phase; records overlay [0..4096)
    // during sweep phase), qn = lds[9216..10240).
    __shared__ float lds[10240];
    float4* rec4 = (float4*)lds;               // 512 records x 2 float4
    float*  red  = lds;                        // red[q*9 + wave]
    float*  qn   = lds + 9216;                 // qn[q], q in [0,1024)

    const int tid  = threadIdx.x;
    const int lane = tid & 63;
    const int wave = __builtin_amdgcn_readfirstlane(tid >> 6);
    const int blk  = blockIdx.x;               // 0..511
    const int dir   = blk >> 8;                // 0: x-queries vs y, 1: y vs x
    const int batch = (blk >> 6) & 3;
    const int qg    = (blk >> 3) & 7;          // query group (1024 q)
    const int seg   = blk & 7;                 // record segment (512 recs)

    const float* qraw = dir ? yraw : xraw;
    const float* oraw = dir ? xraw : yraw;

    // ---- stage: 512 records {x0,y0,z0,w0}{x1,y1,z1,w1}, 1/thread ----
    {
        int r = tid;                           // 0..511
        const float2* p2 = (const float2*)(oraw + ((size_t)batch * N_ + seg * 1024 + 2 * r) * 3);
        float2 a = p2[0], b = p2[1], c = p2[2];   // x0,y0 | z0,x1 | y1,z1
        float w0 = fmaf(a.x, a.x, fmaf(a.y, a.y, b.x * b.x));
        float w1 = fmaf(b.y, b.y, fmaf(c.x, c.x, c.y * c.y));
        rec4[2*r]   = make_float4(a.x, a.y, b.x, w0);
        rec4[2*r+1] = make_float4(b.y, c.x, c.y, w1);
    }

    // ---- queries: strided ownership q = lane + 64j, coalesced b32 loads ----
    const int qbase = batch * N_ + qg * 1024;
    float qx[16], qy[16], qz[16], acc[16];
    #pragma unroll
    for (int j = 0; j < 16; ++j) {
        int q = lane + 64 * j;                 // block-local query index
        const float* qp = qraw + (size_t)(qbase + q) * 3;
        float ax = qp[0], ay = qp[1], az = qp[2];
        qx[j] = -2.0f * ax; qy[j] = -2.0f * ay; qz[j] = -2.0f * az;
        if (wave == 0) qn[q] = fmaf(ax, ax, fmaf(ay, ay, az * az));
        acc[j] = FLT_BIG;
    }
    __syncthreads();

    // ---- sweep: 64 records from LDS, broadcast b128 reads ----
    const float4* rp = rec4 + wave * 128;      // this wave's 64 records
    #pragma unroll 2
    for (int k = 0; k < 64; ++k) {
        float4 u = rp[2*k];                    // {x0,y0,z0,w0}
        float4 v = rp[2*k+1];                  // {x1,y1,z1,w1}
        #pragma unroll
        for (int j = 0; j < 16; ++j) {
            float t0 = fmaf(qz[j], u.z, u.w);
            t0 = fmaf(qy[j], u.y, t0);
            t0 = fmaf(qx[j], u.x, t0);
            float t1 = fmaf(qz[j], v.z, v.w);
            t1 = fmaf(qy[j], v.y, t1);
            t1 = fmaf(qx[j], v.x, t1);
            acc[j] = fminf(acc[j], fminf(t0, t1));   // v_min3_f32
        }
    }
    __syncthreads();                           // records no longer needed

    // ---- write wave partials: red[q*9 + wave], lane-stride 9 (no conflicts) ----
    #pragma unroll
    for (int j = 0; j < 16; ++j) red[(lane + 64 * j) * 9 + wave] = acc[j];
    __syncthreads();

    // ---- combine: thread t owns queries t and t+512 ----
    #pragma unroll
    for (int r2 = 0; r2 < 2; ++r2) {
        int q = r2 * 512 + tid;
        float m = red[q * 9];
        #pragma unroll
        for (int w = 1; w < 8; ++w) m = fminf(m, red[q * 9 + w]);
        float d2 = fmaxf(0.0f, qn[q] + m);     // relu commutes with min
        atomicMin(&pmin[dir * 32768 + qbase + q], __float_as_uint(d2));
    }
}

// ---------------- sum: single block, deterministic ----------------
__global__ __launch_bounds__(1024) void sum_kernel(
    const unsigned int* __restrict__ pmin, float* __restrict__ out)
{
    __shared__ float sred[16];
    const int tid = threadIdx.x;
    const float4* pv = (const float4*)pmin;    // bits are valid non-neg floats
    float s = 0.0f;
    #pragma unroll
    for (int k = 0; k < 16; ++k) {             // 16384 float4 / 1024 threads
        float4 v = pv[k * 1024 + tid];
        s += v.x + v.y + v.z + v.w;
    }
    #pragma unroll
    for (int off = 32; off > 0; off >>= 1) s += __shfl_xor(s, off);
    if ((tid & 63) == 0) sred[tid >> 6] = s;
    __syncthreads();
    if (tid < 16) {
        float v = sred[tid];
        #pragma unroll
        for (int off = 8; off > 0; off >>= 1) v += __shfl_xor(v, off);
        if (tid == 0) *out = v * (1.0f / 32768.0f);
    }
}

// ---------------- fallback (ws too small): round-1 kernel ----------------
__global__ __launch_bounds__(1024) void chamfer_raw_kernel(
    const float* __restrict__ xraw, const float* __restrict__ yraw,
    float* __restrict__ out)
{
    __shared__ float4 red4[16][64];
    const int tid  = threadIdx.x;
    const int wave = tid >> 6;
    const int lane = tid & 63;
    const int blk  = blockIdx.x;
    const bool xdir = (blk < 128);
    const int b    = (blk & 127) >> 5;
    const int qofs = (blk & 31) << 8;
    const float* qraw = xdir ? xraw : yraw;
    const float* oraw = xdir ? yraw : xraw;
    float qx0[4], qx1[4], qx2[4], acc[4];
    #pragma unroll
    for (int q = 0; q < 4; ++q) {
        int gq = b * N_ + qofs + lane*4 + q;
        qx0[q] = qraw[gq*3+0]; qx1[q] = qraw[gq*3+1]; qx2[q] = qraw[gq*3+2];
        acc[q] = FLT_BIG;
    }
    const float* opp = oraw + (size_t)(b * N_ + wave * 512) * 3;
    #pragma unroll 4
    for (int k = 0; k < 512; ++k) {
        float p0 = opp[k*3+0], p1 = opp[k*3+1], p2 = opp[k*3+2];
        float w  = fmaf(p0, p0, fmaf(p1, p1, p2*p2));
        #pragma unroll
        for (int q = 0; q < 4; ++q) {
            float dot = qx0[q]*p0 + qx1[q]*p1 + qx2[q]*p2;
            acc[q] = fminf(acc[q], fmaf(-2.0f, dot, w));
        }
    }
    red4[wave][lane] = make_float4(acc[0], acc[1], acc[2], acc[3]);
    __syncthreads();
    if (tid < 256) {
        const float* red = (const float*)red4;
        float m = red[tid];
        #pragma unroll
        for (int w = 1; w < 16; ++w) m = fminf(m, red[w*256 + tid]);
        int gq = b * N_ + qofs + tid;
        float ax = qraw[gq*3+0], ay = qraw[gq*3+1], az = qraw[gq*3+2];
        float d2 = fmaxf(0.0f, fmaf(ax,ax,fmaf(ay,ay,az*az)) + m);
        #pragma unroll
        for (int off = 32; off > 0; off >>= 1) d2 += __shfl_xor(d2, off);
        if ((tid & 63) == 0) atomicAdd(out, d2 * (1.0f / 32768.0f));
    }
}

extern "C" void kernel_launch(void* const* d_in, const int* in_sizes, int n_in,
                              void* d_out, int out_size, void* d_ws, size_t ws_size,
                              hipStream_t stream)
{
    const float* x = (const float*)d_in[0];
    const float* y = (const float*)d_in[1];
    float* out = (float*)d_out;

    const size_t need = (size_t)NQ * 4;        // 256 KB pmin
    if (ws_size >= need) {
        unsigned int* pmin = (unsigned int*)d_ws;
        init_kernel<<<64, 256, 0, stream>>>(pmin);
        chamfer_kernel<<<512, 512, 0, stream>>>(x, y, pmin);
        sum_kernel<<<1, 1024, 0, stream>>>(pmin, out);
    } else {
        zero_out_kernel<<<1, 1, 0, stream>>>(out);
        chamfer_raw_kernel<<<256, 1024, 0, stream>>>(x, y, out);
    }
}